// Round 8
// baseline (485.978 us; speedup 1.0000x reference)
//
#include <hip/hip_runtime.h>

#define NN 100000
#define NE 1000000
#define NEP (NE + 2 * NN)   // padded edge capacity (<=1 pad per (dst,rel) segment)
#define DIM 64
#define ZPITCH 200          // LDS row pitch in ushort (400 B; 16B-aligned)
#define SCHUNK 1024
#define SBLOCKS ((NN + SCHUNK - 1) / SCHUNK)   // 98
#define PAD2(c) (((c) + 1) & ~1)

typedef __attribute__((ext_vector_type(8))) short short8;
typedef __attribute__((ext_vector_type(4))) float f32x4;

__device__ __forceinline__ float bf2f(ushort u) {
    union { uint i; float f; } c; c.i = ((uint)u) << 16; return c.f;
}
__device__ __forceinline__ ushort f2bf(float f) {
    union { float f; uint i; } c; c.f = f;
    uint u = c.i;
    return (ushort)((u + 0x7FFFu + ((u >> 16) & 1u)) >> 16);   // RNE
}

#define UNPACK_ADD(v, ax, ay) { union {uint u; float f;} lo_, hi_;            \
    lo_.u = (v) << 16; hi_.u = (v) & 0xFFFF0000u; (ax) += lo_.f; (ay) += hi_.f; }

// ---------------- CSR build (per-(dst,etype) counts, even-padded rows) ------
__global__ __launch_bounds__(256) void zero_counts2(int* cnt2) {
    int i = blockIdx.x * 256 + threadIdx.x;
    if (i < 2 * NN) cnt2[i] = 0;
}

__global__ __launch_bounds__(256) void init_esrc(int* esrc) {
    int i = blockIdx.x * 256 + threadIdx.x;
    if (i < NEP) esrc[i] = NN;   // zero-row index (padding target)
}

__global__ __launch_bounds__(256) void count_rank2(const int* __restrict__ dst,
                                                   const int* __restrict__ et,
                                                   int* __restrict__ cnt2,
                                                   int* __restrict__ rank) {
    int e = blockIdx.x * 256 + threadIdx.x;
    if (e < NE) rank[e] = atomicAdd(&cnt2[dst[e] * 2 + et[e]], 1);
}

__global__ __launch_bounds__(256) void scan_partial2p(const int* __restrict__ cnt2,
                                                      int* __restrict__ bsum) {
    int t = threadIdx.x, lane = t & 63, wid = t >> 6;
    int base = blockIdx.x * SCHUNK + t * 4;
    int s = 0;
#pragma unroll
    for (int k = 0; k < 4; ++k) {
        int i = base + k;
        if (i < NN) s += PAD2(cnt2[2 * i]) + PAD2(cnt2[2 * i + 1]);
    }
#pragma unroll
    for (int off = 32; off > 0; off >>= 1) s += __shfl_down(s, off, 64);
    __shared__ int wtot[4];
    if (lane == 0) wtot[wid] = s;
    __syncthreads();
    if (t == 0) bsum[blockIdx.x] = wtot[0] + wtot[1] + wtot[2] + wtot[3];
}

__global__ __launch_bounds__(128) void scan_bsums(const int* __restrict__ bsum,
                                                  int* __restrict__ bsum_ex) {
    __shared__ int sh[128];
    int t = threadIdx.x;
    int v = (t < SBLOCKS) ? bsum[t] : 0;
    sh[t] = v;
    __syncthreads();
    for (int off = 1; off < 128; off <<= 1) {
        int u = (t >= off) ? sh[t - off] : 0;
        __syncthreads();
        sh[t] += u;
        __syncthreads();
    }
    if (t < SBLOCKS) bsum_ex[t] = sh[t] - v;
}

__global__ __launch_bounds__(256) void scan_final2p(const int* __restrict__ cnt2,
                                                    const int* __restrict__ bsum_ex,
                                                    int* __restrict__ row_ptr) {
    int t = threadIdx.x, lane = t & 63, wid = t >> 6;
    int base = blockIdx.x * SCHUNK + t * 4;
    int c[4];
#pragma unroll
    for (int k = 0; k < 4; ++k) {
        int i = base + k;
        c[k] = (i < NN) ? (PAD2(cnt2[2 * i]) + PAD2(cnt2[2 * i + 1])) : 0;
    }
    int s = c[0] + c[1] + c[2] + c[3];
    int incl = s;
#pragma unroll
    for (int off = 1; off < 64; off <<= 1) {
        int u = __shfl_up(incl, off, 64);
        if (lane >= off) incl += u;
    }
    __shared__ int wtot[4];
    if (lane == 63) wtot[wid] = incl;
    __syncthreads();
    int woff = 0;
    for (int w = 0; w < wid; ++w) woff += wtot[w];
    int run = bsum_ex[blockIdx.x] + woff + (incl - s);
#pragma unroll
    for (int k = 0; k < 4; ++k) {
        int i = base + k;
        if (i < NN) row_ptr[i] = run;
        run += c[k];
    }
}

// Fill: rel-0 edges first, then rel-1 (at padded offset). Pad slots keep NN.
__global__ __launch_bounds__(256) void fill_edges4(const int* __restrict__ src,
                                                   const int* __restrict__ dst,
                                                   const int* __restrict__ et,
                                                   const int* __restrict__ rank,
                                                   const int* __restrict__ row_ptr,
                                                   const int* __restrict__ cnt2,
                                                   int* __restrict__ esrc) {
    int e = blockIdx.x * 256 + threadIdx.x;
    if (e < NE) {
        int d = dst[e], r = et[e];
        int pos = row_ptr[d] + rank[e] + (r ? PAD2(cnt2[2 * d]) : 0);
        esrc[pos] = src[e];
    }
}

// ---------------- Feature convert + zero-row maintenance ----------------
__global__ __launch_bounds__(256) void convert_feat(const float* __restrict__ x,
                                                    ushort* __restrict__ xb) {
    int i = blockIdx.x * 256 + threadIdx.x;   // over NN*16 float4s (exact)
    float4 v = ((const float4*)x)[i];
    union { ushort u[4]; uint2 w; } o;
    o.u[0] = f2bf(v.x); o.u[1] = f2bf(v.y); o.u[2] = f2bf(v.z); o.u[3] = f2bf(v.w);
    *(uint2*)(xb + (size_t)i * 4) = o.w;
}

// Row NN of both feature tables must be zero (padding gather target);
// workspace is re-poisoned before every call.
__global__ void zero_rows(ushort* a, ushort* b) {
    int t = threadIdx.x;   // 64 threads
    a[(size_t)NN * DIM + t] = 0;
    b[(size_t)NN * DIM + t] = 0;
}

// ---------------- Weight prep: hi/lo bf16 split of [W0;W1;Ws] ----------------
__global__ __launch_bounds__(256) void prep_w(const float* __restrict__ W,
                                              const float* __restrict__ Ws,
                                              ushort* __restrict__ wt) {
    int idx = blockIdx.x * 256 + threadIdx.x;  // 0..12287 (grid 48)
    int k = idx >> 6, n = idx & 63;
    float v = (k < 128) ? W[k * 64 + n] : Ws[(k - 128) * 64 + n];
    ushort h = f2bf(v);
    ushort l = f2bf(v - bf2f(h));
    wt[n * 192 + k] = h;
    wt[12288 + n * 192 + k] = l;
}

// ---------------- Fused layer: aggregate (gather) + MFMA transform ----------
// Block = 256 thr = 4 waves; 64-node tile. Wave w aggregates nodes
// [n0+16w, n0+16w+16) into sZ cols 0..127 (bf16-packed per-relation sums);
// self rows staged into cols 128..191. Then barrier + 192x64 MFMA GEMM
// (hi/lo bf16 weight split) -> out.
// Per-pair gather: half-wave h handles edge j+h; edge idx via v_readlane
// (uniform j); rows even-padded -> no tails, relation-pure pairs.
__global__ __launch_bounds__(256) void rgcn_layer(
    const uint* __restrict__ xbu,     // (NN+1) x 32 uint (bf16x2) feature table
    const int* __restrict__ row_ptr,
    const int* __restrict__ cnt2,
    const int* __restrict__ esrc,
    const ushort* __restrict__ wt,    // [2][64][192] bf16 (hi, lo)
    const float* __restrict__ bias,
    float* __restrict__ outf,         // mode 1
    ushort* __restrict__ xbn,         // mode 0: next-layer table (bf16 relu)
    int mode)
{
    __shared__ ushort sZ[64 * ZPITCH];   // 25.6 KB
    uint* sZu = (uint*)sZ;               // pitch 100 uints

    int t = threadIdx.x, lane = t & 63, wid = t >> 6;
    int sl = lane & 31, h = lane >> 5;
    int n0 = blockIdx.x * 64;

    // Stage self rows (cols 128..191), block-wide coalesced.
    {
        const ushort* xb = (const ushort*)xbu;
        for (int i = t; i < 512; i += 256) {            // 64 rows x 8 uint4
            int node = i >> 3, c8 = i & 7;
            int n = n0 + node;
            uint4 v = {0u, 0u, 0u, 0u};
            if (n < NN) v = *(const uint4*)(xb + (size_t)n * DIM + c8 * 8);
            *(uint4*)(sZ + node * ZPITCH + 128 + c8 * 8) = v;
        }
    }

    // Aggregate 16 nodes per wave into sZ cols 0..127.
    const uint* xrow = xbu + sl;
    for (int i = 0; i < 16; ++i) {
        int nl = wid * 16 + i;
        int n = n0 + nl;
        float a00 = 0.f, a01 = 0.f, a10 = 0.f, a11 = 0.f;
        if (n < NN) {
            int start = row_ptr[n];
            int c0p = PAD2(cnt2[2 * n]);
            int c1p = PAD2(cnt2[2 * n + 1]);
            int degp = c0p + c1p;
            for (int base = 0; base < degp; base += 64) {
                int rem = degp - base; if (rem > 64) rem = 64;
                int ev = (lane < rem) ? esrc[start + base + lane] : 0;
                int b0 = c0p - base;
                if (b0 < 0) b0 = 0; if (b0 > rem) b0 = rem;   // even
                int j = 0;
#pragma unroll 2
                for (; j < b0; j += 2) {                      // relation 0
                    int p0 = __builtin_amdgcn_readlane(ev, j);
                    int p1 = __builtin_amdgcn_readlane(ev, j + 1);
                    uint v = xrow[(uint)((h ? p1 : p0) << 5)];
                    UNPACK_ADD(v, a00, a01);
                }
#pragma unroll 2
                for (; j < rem; j += 2) {                     // relation 1
                    int p0 = __builtin_amdgcn_readlane(ev, j);
                    int p1 = __builtin_amdgcn_readlane(ev, j + 1);
                    uint v = xrow[(uint)((h ? p1 : p0) << 5)];
                    UNPACK_ADD(v, a10, a11);
                }
            }
            a00 += __shfl_xor(a00, 32, 64);
            a01 += __shfl_xor(a01, 32, 64);
            a10 += __shfl_xor(a10, 32, 64);
            a11 += __shfl_xor(a11, 32, 64);
        }
        float ox = h ? a10 : a00, oy = h ? a11 : a01;
        sZu[nl * 100 + lane] = ((uint)f2bf(oy) << 16) | (uint)f2bf(ox);
    }
    __syncthreads();

    // MFMA transform (B-frags loaded after barrier: short live range).
    int quad = lane >> 4, l16 = lane & 15;
    short8 bh[6], bl[6];
    {
        const ushort* wh = wt + (size_t)(wid * 16 + l16) * 192;
        const ushort* wl = wh + 64 * 192;
#pragma unroll
        for (int kk = 0; kk < 6; ++kk) {
            bh[kk] = *(const short8*)(wh + kk * 32 + quad * 8);
            bl[kk] = *(const short8*)(wl + kk * 32 + quad * 8);
        }
    }
    float bv = bias[wid * 16 + l16];

    f32x4 acc[4];
#pragma unroll
    for (int mt = 0; mt < 4; ++mt) acc[mt] = (f32x4){bv, bv, bv, bv};

#pragma unroll
    for (int kk = 0; kk < 6; ++kk) {
#pragma unroll
        for (int mt = 0; mt < 4; ++mt) {
            short8 a = *(const short8*)(sZ + (mt * 16 + l16) * ZPITCH + kk * 32 + quad * 8);
            acc[mt] = __builtin_amdgcn_mfma_f32_16x16x32_bf16(a, bh[kk], acc[mt], 0, 0, 0);
            acc[mt] = __builtin_amdgcn_mfma_f32_16x16x32_bf16(a, bl[kk], acc[mt], 0, 0, 0);
        }
    }

    int col = wid * 16 + l16;
#pragma unroll
    for (int mt = 0; mt < 4; ++mt) {
#pragma unroll
        for (int r = 0; r < 4; ++r) {
            int node = n0 + mt * 16 + quad * 4 + r;
            if (node < NN) {
                float v = acc[mt][r];
                if (mode) outf[(size_t)node * DIM + col] = v;
                else      xbn[(size_t)node * DIM + col] = f2bf(fmaxf(v, 0.f));
            }
        }
    }
}

extern "C" void kernel_launch(void* const* d_in, const int* in_sizes, int n_in,
                              void* d_out, int out_size, void* d_ws, size_t ws_size,
                              hipStream_t stream)
{
    const float* feat = (const float*)d_in[0];
    const int*   src  = (const int*)d_in[1];
    const int*   dst  = (const int*)d_in[2];
    const int*   et   = (const int*)d_in[3];
    const float* W[3]  = { (const float*)d_in[4], (const float*)d_in[7], (const float*)d_in[10] };
    const float* Ws[3] = { (const float*)d_in[5], (const float*)d_in[8], (const float*)d_in[11] };
    const float* b[3]  = { (const float*)d_in[6], (const float*)d_in[9], (const float*)d_in[12] };

    // Workspace (~36 MB):
    //   xbuf0/xbuf1 ushort[(NN+1)*64]  2 x 12.8 MB  (row NN = zero row)
    //   wt ushort[3][2*12288]
    //   esrc int[NEP]; rank int[NE]; cnt2 int[2NN]; row_ptr int[NN]; bsum/bsum_ex
    ushort* xbuf0 = (ushort*)d_ws;
    ushort* xbuf1 = xbuf0 + (size_t)(NN + 1) * DIM;
    ushort* wt    = xbuf1 + (size_t)(NN + 1) * DIM;
    int* esrc    = (int*)(wt + 3 * 2 * 12288);
    int* rank    = esrc + NEP;
    int* cnt2    = rank + NE;
    int* row_ptr = cnt2 + 2 * NN;
    int* bsum    = row_ptr + NN;
    int* bsum_ex = bsum + SBLOCKS;
    float* outF  = (float*)d_out;

    const dim3 tb(256);
    const int zgrid = (2 * NN + 255) / 256;   // 782
    const int igrid = (NEP + 255) / 256;      // 4688
    const int egrid = (NE + 255) / 256;       // 3907
    const int lgrid = (NN + 63) / 64;         // 1563

    // CSR build (relation-sorted, even-padded rows)
    zero_counts2<<<zgrid, tb, 0, stream>>>(cnt2);
    init_esrc<<<igrid, tb, 0, stream>>>(esrc);
    count_rank2<<<egrid, tb, 0, stream>>>(dst, et, cnt2, rank);
    scan_partial2p<<<SBLOCKS, tb, 0, stream>>>(cnt2, bsum);
    scan_bsums<<<1, 128, 0, stream>>>(bsum, bsum_ex);
    scan_final2p<<<SBLOCKS, tb, 0, stream>>>(cnt2, bsum_ex, row_ptr);
    fill_edges4<<<egrid, tb, 0, stream>>>(src, dst, et, rank, row_ptr, cnt2, esrc);

    prep_w<<<48, tb, 0, stream>>>(W[0], Ws[0], wt);
    prep_w<<<48, tb, 0, stream>>>(W[1], Ws[1], wt + 2 * 12288);
    prep_w<<<48, tb, 0, stream>>>(W[2], Ws[2], wt + 4 * 12288);
    convert_feat<<<NN * 16 / 256, tb, 0, stream>>>(feat, xbuf0);
    zero_rows<<<1, 64, 0, stream>>>(xbuf0, xbuf1);

    // Layer 0: xbuf0 -> xbuf1 = bf16(relu(out0))
    rgcn_layer<<<lgrid, tb, 0, stream>>>((const uint*)xbuf0, row_ptr, cnt2, esrc,
                                         wt, b[0], nullptr, xbuf1, 0);
    // Layer 1: xbuf1 -> xbuf0
    rgcn_layer<<<lgrid, tb, 0, stream>>>((const uint*)xbuf1, row_ptr, cnt2, esrc,
                                         wt + 2 * 12288, b[1], nullptr, xbuf0, 0);
    // Layer 2: xbuf0 -> d_out (fp32, no activation)
    rgcn_layer<<<lgrid, tb, 0, stream>>>((const uint*)xbuf0, row_ptr, cnt2, esrc,
                                         wt + 4 * 12288, b[2], outF, nullptr, 1);
}

// Round 9
// 365.071 us; speedup vs baseline: 1.3312x; 1.3312x over previous
//
#include <hip/hip_runtime.h>

#define NN 100000
#define NE 1000000
#define NEP (NE + 6 * NN)   // padded capacity (<=3 pads per (dst,rel) segment)
#define DIM 64
#define ZPITCH 200          // LDS row pitch in ushort for transform tile
#define SCHUNK 1024
#define SBLOCKS ((NN + SCHUNK - 1) / SCHUNK)   // 98
#define PAD4(c) (((c) + 3) & ~3)

typedef __attribute__((ext_vector_type(8))) short short8;
typedef __attribute__((ext_vector_type(4))) float f32x4;

__device__ __forceinline__ float bf2f(ushort u) {
    union { uint i; float f; } c; c.i = ((uint)u) << 16; return c.f;
}
__device__ __forceinline__ ushort f2bf(float f) {
    union { float f; uint i; } c; c.f = f;
    uint u = c.i;
    return (ushort)((u + 0x7FFFu + ((u >> 16) & 1u)) >> 16);   // RNE
}

#define UNPACK_ADD(v, ax, ay) { union {uint u; float f;} lo_, hi_;            \
    lo_.u = (v) << 16; hi_.u = (v) & 0xFFFF0000u; (ax) += lo_.f; (ay) += hi_.f; }

// ---------------- CSR build (per-(dst,etype) counts, 4-padded segments) -----
__global__ __launch_bounds__(256) void zero_counts2(int* cnt2) {
    int i = blockIdx.x * 256 + threadIdx.x;
    if (i < 2 * NN) cnt2[i] = 0;
}

__global__ __launch_bounds__(256) void init_esrc(int* esrc) {
    int i = blockIdx.x * 256 + threadIdx.x;
    if (i < NEP) esrc[i] = NN;   // zero-row index (padding gather target)
}

__global__ __launch_bounds__(256) void count_rank2(const int* __restrict__ dst,
                                                   const int* __restrict__ et,
                                                   int* __restrict__ cnt2,
                                                   int* __restrict__ rank) {
    int e = blockIdx.x * 256 + threadIdx.x;
    if (e < NE) rank[e] = atomicAdd(&cnt2[dst[e] * 2 + et[e]], 1);
}

__global__ __launch_bounds__(256) void scan_partial2p(const int* __restrict__ cnt2,
                                                      int* __restrict__ bsum) {
    int t = threadIdx.x, lane = t & 63, wid = t >> 6;
    int base = blockIdx.x * SCHUNK + t * 4;
    int s = 0;
#pragma unroll
    for (int k = 0; k < 4; ++k) {
        int i = base + k;
        if (i < NN) s += PAD4(cnt2[2 * i]) + PAD4(cnt2[2 * i + 1]);
    }
#pragma unroll
    for (int off = 32; off > 0; off >>= 1) s += __shfl_down(s, off, 64);
    __shared__ int wtot[4];
    if (lane == 0) wtot[wid] = s;
    __syncthreads();
    if (t == 0) bsum[blockIdx.x] = wtot[0] + wtot[1] + wtot[2] + wtot[3];
}

__global__ __launch_bounds__(128) void scan_bsums(const int* __restrict__ bsum,
                                                  int* __restrict__ bsum_ex) {
    __shared__ int sh[128];
    int t = threadIdx.x;
    int v = (t < SBLOCKS) ? bsum[t] : 0;
    sh[t] = v;
    __syncthreads();
    for (int off = 1; off < 128; off <<= 1) {
        int u = (t >= off) ? sh[t - off] : 0;
        __syncthreads();
        sh[t] += u;
        __syncthreads();
    }
    if (t < SBLOCKS) bsum_ex[t] = sh[t] - v;
}

__global__ __launch_bounds__(256) void scan_final2p(const int* __restrict__ cnt2,
                                                    const int* __restrict__ bsum_ex,
                                                    int* __restrict__ row_ptr) {
    int t = threadIdx.x, lane = t & 63, wid = t >> 6;
    int base = blockIdx.x * SCHUNK + t * 4;
    int c[4];
#pragma unroll
    for (int k = 0; k < 4; ++k) {
        int i = base + k;
        c[k] = (i < NN) ? (PAD4(cnt2[2 * i]) + PAD4(cnt2[2 * i + 1])) : 0;
    }
    int s = c[0] + c[1] + c[2] + c[3];
    int incl = s;
#pragma unroll
    for (int off = 1; off < 64; off <<= 1) {
        int u = __shfl_up(incl, off, 64);
        if (lane >= off) incl += u;
    }
    __shared__ int wtot[4];
    if (lane == 63) wtot[wid] = incl;
    __syncthreads();
    int woff = 0;
    for (int w = 0; w < wid; ++w) woff += wtot[w];
    int run = bsum_ex[blockIdx.x] + woff + (incl - s);
#pragma unroll
    for (int k = 0; k < 4; ++k) {
        int i = base + k;
        if (i < NN) row_ptr[i] = run;
        run += c[k];
    }
}

// Fill: rel-0 edges first, then rel-1 (at 4-padded offset). Pads keep NN.
__global__ __launch_bounds__(256) void fill_edges4(const int* __restrict__ src,
                                                   const int* __restrict__ dst,
                                                   const int* __restrict__ et,
                                                   const int* __restrict__ rank,
                                                   const int* __restrict__ row_ptr,
                                                   const int* __restrict__ cnt2,
                                                   int* __restrict__ esrc) {
    int e = blockIdx.x * 256 + threadIdx.x;
    if (e < NE) {
        int d = dst[e], r = et[e];
        int pos = row_ptr[d] + rank[e] + (r ? PAD4(cnt2[2 * d]) : 0);
        esrc[pos] = src[e];
    }
}

// ---------------- Feature convert + zero-row maintenance ----------------
__global__ __launch_bounds__(256) void convert_feat(const float* __restrict__ x,
                                                    ushort* __restrict__ xb) {
    int i = blockIdx.x * 256 + threadIdx.x;   // over NN*16 float4s (exact)
    float4 v = ((const float4*)x)[i];
    union { ushort u[4]; uint2 w; } o;
    o.u[0] = f2bf(v.x); o.u[1] = f2bf(v.y); o.u[2] = f2bf(v.z); o.u[3] = f2bf(v.w);
    *(uint2*)(xb + (size_t)i * 4) = o.w;
}

// Row NN of both feature tables must be zero (padding gather target).
__global__ void zero_rows(ushort* a, ushort* b) {
    int t = threadIdx.x;   // 64 threads
    a[(size_t)NN * DIM + t] = 0;
    b[(size_t)NN * DIM + t] = 0;
}

// ---------------- Weight prep: hi/lo bf16 split of [W0;W1;Ws] ----------------
__global__ __launch_bounds__(256) void prep_w(const float* __restrict__ W,
                                              const float* __restrict__ Ws,
                                              ushort* __restrict__ wt) {
    int idx = blockIdx.x * 256 + threadIdx.x;  // 0..12287 (grid 48)
    int k = idx >> 6, n = idx & 63;
    float v = (k < 128) ? W[k * 64 + n] : Ws[(k - 128) * 64 + n];
    ushort h = f2bf(v);
    ushort l = f2bf(v - bf2f(h));
    wt[n * 192 + k] = h;
    wt[12288 + n * 192 + k] = l;
}

// ---------------- Aggregation v5: quad-gather, 16 lanes/edge ----------------
// xb2: (NN+1)-row table viewed as uint2 (4 dims / 8 B per element, 16/row).
// One wave per node. Each iteration gathers FOUR edges: lane-group g = lane>>4
// handles edge j+g; lane's uint2 covers dims 4s..4s+3 (s = lane&15).
// Edge indices via v_readlane (uniform j) + 3 cndmask select -> 4 independent
// 128B row-gathers in flight per load instruction (8 with unroll 2).
// Segments 4-padded and relation-sorted -> all quads relation-pure, loop
// control wave-uniform. Group sums combined via shfl_xor(16,32) once per node.
__global__ __launch_bounds__(256) void rgcn_aggregate_q(
    const uint2* __restrict__ xb2, const int* __restrict__ row_ptr,
    const int* __restrict__ cnt2, const int* __restrict__ esrc,
    uint2* __restrict__ agg2)      // NN x 32 uint2: [rel0 16 | rel1 16]
{
    int t = threadIdx.x, lane = t & 63, wid = t >> 6;
    int n = blockIdx.x * 4 + wid;
    if (n >= NN) return;
    int g = lane >> 4, s = lane & 15;
    int start = row_ptr[n];
    int c0p = PAD4(cnt2[2 * n]);
    int c1p = PAD4(cnt2[2 * n + 1]);
    int degp = c0p + c1p;

    const uint2* xrow = xb2 + s;
    float a0[4] = {0.f, 0.f, 0.f, 0.f};
    float a1[4] = {0.f, 0.f, 0.f, 0.f};

    for (int base = 0; base < degp; base += 64) {
        int rem = degp - base; if (rem > 64) rem = 64;
        int ev = (lane < rem) ? esrc[start + base + lane] : (int)NN;
        int b0 = c0p - base;
        if (b0 < 0) b0 = 0; if (b0 > rem) b0 = rem;   // multiple of 4
        int j = 0;
#pragma unroll 2
        for (; j < b0; j += 4) {                      // relation 0 quads
            int p0 = __builtin_amdgcn_readlane(ev, j);
            int p1 = __builtin_amdgcn_readlane(ev, j + 1);
            int p2 = __builtin_amdgcn_readlane(ev, j + 2);
            int p3 = __builtin_amdgcn_readlane(ev, j + 3);
            int pa = (g & 1) ? p1 : p0;
            int pb = (g & 1) ? p3 : p2;
            int p  = (g & 2) ? pb : pa;
            uint2 v = xrow[(size_t)p * 16];
            UNPACK_ADD(v.x, a0[0], a0[1]);
            UNPACK_ADD(v.y, a0[2], a0[3]);
        }
#pragma unroll 2
        for (; j < rem; j += 4) {                     // relation 1 quads
            int p0 = __builtin_amdgcn_readlane(ev, j);
            int p1 = __builtin_amdgcn_readlane(ev, j + 1);
            int p2 = __builtin_amdgcn_readlane(ev, j + 2);
            int p3 = __builtin_amdgcn_readlane(ev, j + 3);
            int pa = (g & 1) ? p1 : p0;
            int pb = (g & 1) ? p3 : p2;
            int p  = (g & 2) ? pb : pa;
            uint2 v = xrow[(size_t)p * 16];
            UNPACK_ADD(v.x, a1[0], a1[1]);
            UNPACK_ADD(v.y, a1[2], a1[3]);
        }
    }

#pragma unroll
    for (int d = 0; d < 4; ++d) {                     // combine 4 groups
        a0[d] += __shfl_xor(a0[d], 16, 64);
        a0[d] += __shfl_xor(a0[d], 32, 64);
        a1[d] += __shfl_xor(a1[d], 16, 64);
        a1[d] += __shfl_xor(a1[d], 32, 64);
    }

    // Row layout (matches transform): 128 bf16 = [rel0 dims 0..63 | rel1].
    // Group 0 writes rel0 uint2 s (dims 4s..4s+3); group 1 writes rel1.
    if (g < 2) {
        const float* a = g ? a1 : a0;
        uint2 o;
        o.x = ((uint)f2bf(a[1]) << 16) | (uint)f2bf(a[0]);
        o.y = ((uint)f2bf(a[3]) << 16) | (uint)f2bf(a[2]);
        agg2[(size_t)n * 32 + g * 16 + s] = o;
    }
}

// ---------------- MFMA transform (unchanged from R7) ----------------
__global__ __launch_bounds__(256) void rgcn_transform_mfma(
    const ushort* __restrict__ agg,   // [NN][128] bf16
    const ushort* __restrict__ xb,    // [NN][64]  bf16
    const ushort* __restrict__ wt,    // [2][64][192] bf16 (hi, lo)
    const float* __restrict__ bias,
    float* __restrict__ outf,
    ushort* __restrict__ xbn,
    int mode)
{
    __shared__ ushort sZ[64 * ZPITCH];   // 25.6 KB

    int t = threadIdx.x, lane = t & 63, wid = t >> 6;
    int quad = lane >> 4, l16 = lane & 15;

    short8 bh[6], bl[6];
    {
        const ushort* wh = wt + (size_t)(wid * 16 + l16) * 192;
        const ushort* wl = wh + 64 * 192;
#pragma unroll
        for (int kk = 0; kk < 6; ++kk) {
            bh[kk] = *(const short8*)(wh + kk * 32 + quad * 8);
            bl[kk] = *(const short8*)(wl + kk * 32 + quad * 8);
        }
    }
    float bv = bias[wid * 16 + l16];

    int n0 = blockIdx.x * 64;
    for (int i = t; i < 1024; i += 256) {           // agg: 64 rows x 16 uint4
        int node = i >> 4, c8 = i & 15;
        int n = n0 + node;
        uint4 v = {0u, 0u, 0u, 0u};
        if (n < NN) v = *(const uint4*)(agg + (size_t)n * 128 + c8 * 8);
        *(uint4*)(sZ + node * ZPITCH + c8 * 8) = v;
    }
    for (int i = t; i < 512; i += 256) {            // xb: 64 rows x 8 uint4
        int node = i >> 3, c8 = i & 7;
        int n = n0 + node;
        uint4 v = {0u, 0u, 0u, 0u};
        if (n < NN) v = *(const uint4*)(xb + (size_t)n * DIM + c8 * 8);
        *(uint4*)(sZ + node * ZPITCH + 128 + c8 * 8) = v;
    }
    __syncthreads();

    f32x4 acc[4];
#pragma unroll
    for (int mt = 0; mt < 4; ++mt) acc[mt] = (f32x4){bv, bv, bv, bv};

#pragma unroll
    for (int kk = 0; kk < 6; ++kk) {
#pragma unroll
        for (int mt = 0; mt < 4; ++mt) {
            short8 a = *(const short8*)(sZ + (mt * 16 + l16) * ZPITCH + kk * 32 + quad * 8);
            acc[mt] = __builtin_amdgcn_mfma_f32_16x16x32_bf16(a, bh[kk], acc[mt], 0, 0, 0);
            acc[mt] = __builtin_amdgcn_mfma_f32_16x16x32_bf16(a, bl[kk], acc[mt], 0, 0, 0);
        }
    }

    int col = wid * 16 + l16;
#pragma unroll
    for (int mt = 0; mt < 4; ++mt) {
#pragma unroll
        for (int r = 0; r < 4; ++r) {
            int node = n0 + mt * 16 + quad * 4 + r;
            if (node < NN) {
                float v = acc[mt][r];
                if (mode) outf[(size_t)node * DIM + col] = v;
                else      xbn[(size_t)node * DIM + col] = f2bf(fmaxf(v, 0.f));
            }
        }
    }
}

extern "C" void kernel_launch(void* const* d_in, const int* in_sizes, int n_in,
                              void* d_out, int out_size, void* d_ws, size_t ws_size,
                              hipStream_t stream)
{
    const float* feat = (const float*)d_in[0];
    const int*   src  = (const int*)d_in[1];
    const int*   dst  = (const int*)d_in[2];
    const int*   et   = (const int*)d_in[3];
    const float* W[3]  = { (const float*)d_in[4], (const float*)d_in[7], (const float*)d_in[10] };
    const float* Ws[3] = { (const float*)d_in[5], (const float*)d_in[8], (const float*)d_in[11] };
    const float* b[3]  = { (const float*)d_in[6], (const float*)d_in[9], (const float*)d_in[12] };

    // Workspace (~63 MB):
    //   agg   uint[NN*64]           25.6 MB
    //   xbuf0/xbuf1 ushort[(NN+1)*64] 2 x 12.8 MB (row NN = zero row)
    //   wt ushort[3][2*12288]
    //   esrc int[NEP]; rank int[NE]; cnt2 int[2NN]; row_ptr int[NN]; bsum/bsum_ex
    uint*   agg   = (uint*)d_ws;
    ushort* xbuf0 = (ushort*)(agg + (size_t)NN * 64);
    ushort* xbuf1 = xbuf0 + (size_t)(NN + 1) * DIM;
    ushort* wt    = xbuf1 + (size_t)(NN + 1) * DIM;
    int* esrc    = (int*)(wt + 3 * 2 * 12288);
    int* rank    = esrc + NEP;
    int* cnt2    = rank + NE;
    int* row_ptr = cnt2 + 2 * NN;
    int* bsum    = row_ptr + NN;
    int* bsum_ex = bsum + SBLOCKS;
    float* outF  = (float*)d_out;

    const dim3 tb(256);
    const int zgrid = (2 * NN + 255) / 256;   // 782
    const int igrid = (NEP + 255) / 256;      // 6250
    const int egrid = (NE + 255) / 256;       // 3907
    const int tgrid = (NN + 63) / 64;         // 1563
    const int agrid = NN / 4;                 // 25000

    // CSR build (relation-sorted, 4-padded segments)
    zero_counts2<<<zgrid, tb, 0, stream>>>(cnt2);
    init_esrc<<<igrid, tb, 0, stream>>>(esrc);
    count_rank2<<<egrid, tb, 0, stream>>>(dst, et, cnt2, rank);
    scan_partial2p<<<SBLOCKS, tb, 0, stream>>>(cnt2, bsum);
    scan_bsums<<<1, 128, 0, stream>>>(bsum, bsum_ex);
    scan_final2p<<<SBLOCKS, tb, 0, stream>>>(cnt2, bsum_ex, row_ptr);
    fill_edges4<<<egrid, tb, 0, stream>>>(src, dst, et, rank, row_ptr, cnt2, esrc);

    prep_w<<<48, tb, 0, stream>>>(W[0], Ws[0], wt);
    prep_w<<<48, tb, 0, stream>>>(W[1], Ws[1], wt + 2 * 12288);
    prep_w<<<48, tb, 0, stream>>>(W[2], Ws[2], wt + 4 * 12288);
    convert_feat<<<NN * 16 / 256, tb, 0, stream>>>(feat, xbuf0);
    zero_rows<<<1, 64, 0, stream>>>(xbuf0, xbuf1);

    // Layer 0: xbuf0 -> xbuf1 = bf16(relu(out0))
    rgcn_aggregate_q<<<agrid, tb, 0, stream>>>((const uint2*)xbuf0, row_ptr, cnt2, esrc, (uint2*)agg);
    rgcn_transform_mfma<<<tgrid, tb, 0, stream>>>((const ushort*)agg, xbuf0, wt, b[0], nullptr, xbuf1, 0);
    // Layer 1: xbuf1 -> xbuf0
    rgcn_aggregate_q<<<agrid, tb, 0, stream>>>((const uint2*)xbuf1, row_ptr, cnt2, esrc, (uint2*)agg);
    rgcn_transform_mfma<<<tgrid, tb, 0, stream>>>((const ushort*)agg, xbuf1, wt + 2 * 12288, b[1], nullptr, xbuf0, 0);
    // Layer 2: xbuf0 -> d_out (fp32, no activation)
    rgcn_aggregate_q<<<agrid, tb, 0, stream>>>((const uint2*)xbuf0, row_ptr, cnt2, esrc, (uint2*)agg);
    rgcn_transform_mfma<<<tgrid, tb, 0, stream>>>((const ushort*)agg, xbuf0, wt + 4 * 12288, b[2], outF, nullptr, 1);
}